// Round 3
// baseline (400.420 us; speedup 1.0000x reference)
//
#include <hip/hip_runtime.h>

// ObjectMeanDirectAttention — Round 3: barrier-free wave-private attention MLP.
// - Wave w owns nodes 16w..16w+15 end-to-end: L1 MFMA -> L2+L3 -> scatter. No __syncthreads anywhere.
// - x A-fragments loaded directly from global (f32) and converted in-reg; no x staging.
// - W1/W2 pre-transposed to bf16 once into ws (16 KB, L1-resident); B-frags = 1 dwordx4 each.
// - H1 transpose roundtrip via per-wave 16x64 LDS region, XOR-swizzled (col ^ ((row&7)<<3)).
// - LDS 16.5 KB, __launch_bounds__(512,8) -> 4 blocks/CU = 32 waves/CU.

#define NGRAPHS 4096
#define TILE_N 128
constexpr int LDP = 68;    // f32 LDS stride, final MLP
constexpr int LDU = 132;   // f32 LDS stride, 128-wide u tile

typedef short bf16x8 __attribute__((ext_vector_type(8)));
typedef float f32x4 __attribute__((ext_vector_type(4)));

__device__ __forceinline__ unsigned short f2bf(float f) {
    unsigned u = __float_as_uint(f);
    return (unsigned short)((u + 0x7FFFu + ((u >> 16) & 1u)) >> 16);  // RNE
}

__device__ __forceinline__ bf16x8 pack8(float4 a, float4 b) {
    bf16x8 r;
    r[0] = (short)f2bf(a.x); r[1] = (short)f2bf(a.y); r[2] = (short)f2bf(a.z); r[3] = (short)f2bf(a.w);
    r[4] = (short)f2bf(b.x); r[5] = (short)f2bf(b.y); r[6] = (short)f2bf(b.z); r[7] = (short)f2bf(b.w);
    return r;
}

__device__ __forceinline__ int lower_bound_i(const int* __restrict__ arr, int n, int v) {
    int lo = 0, hi = n;
    while (lo < hi) {
        int mid = (lo + hi) >> 1;
        if (arr[mid] < v) lo = mid + 1; else hi = mid;
    }
    return lo;
}

// one-shot: w1t[j*64+k] = bf16(W1[k*64+j]), same for W2 (16 KB total in ws)
__global__ __launch_bounds__(256)
void convert_weights_kernel(const float* __restrict__ W1, const float* __restrict__ W2,
                            unsigned short* __restrict__ w1t, unsigned short* __restrict__ w2t) {
    int e = blockIdx.x * 256 + threadIdx.x;     // 0..4095
    int j = e >> 6, k = e & 63;
    w1t[e] = f2bf(W1[k * 64 + j]);
    w2t[e] = f2bf(W2[k * 64 + j]);
}

// ---------------- attention MLP + weighted scatter (barrier-free) ----------------
__global__ __launch_bounds__(512, 8)
void attn_scatter_mfma(const float* __restrict__ x, const int* __restrict__ batch, int N,
                       const unsigned short* __restrict__ w1t, const unsigned short* __restrict__ w2t,
                       const float* __restrict__ b1, const float* __restrict__ b2,
                       const float* __restrict__ W3, const float* __restrict__ b3,
                       float* __restrict__ num, int col_off) {
    __shared__ unsigned short H1[8][16 * 64];   // per-wave 16x64 bf16, XOR-swizzled cols
    __shared__ float a_s[8][16];                // per-wave attention scalars

    const int t = threadIdx.x;
    const int w = t >> 6;          // wave 0..7 owns rows 16w..16w+15
    const int l = t & 63;
    const int jj = l & 15;         // A row-in-tile / B col-in-tile
    const int kb = l >> 4;         // k-block 0..3
    const int base = blockIdx.x * TILE_N;
    const int nvalid = min(TILE_N, N - base);
    const int rowA = base + w * 16 + jj;

    // per-lane bias / W3 slices (f32, L1-resident)
    float b1c[4], b2c[4], w3c[4];
#pragma unroll
    for (int ct = 0; ct < 4; ct++) {
        b1c[ct] = b1[ct * 16 + jj];
        b2c[ct] = b2[ct * 16 + jj];
        w3c[ct] = W3[ct * 16 + jj];
    }
    const float b3v = b3[0];

    // A-fragments of x direct from global: lane (jj,kb) covers row rowA, cols kb*8..+7 and 32+kb*8..+7
    float4 v0 = make_float4(0.f, 0.f, 0.f, 0.f), v1 = v0, v2 = v0, v3 = v0;
    if (rowA < N) {
        const float* xr = x + (size_t)rowA * 64;
        v0 = *(const float4*)&xr[kb * 8];
        v1 = *(const float4*)&xr[kb * 8 + 4];
        v2 = *(const float4*)&xr[32 + kb * 8];
        v3 = *(const float4*)&xr[32 + kb * 8 + 4];
    }
    const bf16x8 ax0 = pack8(v0, v1);
    const bf16x8 ax1 = pack8(v2, v3);

    unsigned short* H1w = H1[w];

    // ---- layer 1: H1 = relu(x @ W1 + b1); C/D: col=jj, row=kb*4+reg
#pragma unroll
    for (int ct = 0; ct < 4; ct++) {
        const int wrow = (ct * 16 + jj) * 64 + kb * 8;
        bf16x8 bw0 = *(const bf16x8*)&w1t[wrow];
        bf16x8 bw1 = *(const bf16x8*)&w1t[wrow + 32];
        f32x4 acc = {0.f, 0.f, 0.f, 0.f};
        acc = __builtin_amdgcn_mfma_f32_16x16x32_bf16(ax0, bw0, acc, 0, 0, 0);
        acc = __builtin_amdgcn_mfma_f32_16x16x32_bf16(ax1, bw1, acc, 0, 0, 0);
#pragma unroll
        for (int reg = 0; reg < 4; reg++) {
            const int r = kb * 4 + reg;
            float h = fmaxf(acc[reg] + b1c[ct], 0.f);
            H1w[r * 64 + ((ct * 16 + jj) ^ ((r & 7) << 3))] = f2bf(h);
        }
    }
    // same-wave LDS RAW: compiler inserts lgkmcnt wait (no barrier needed, H1w is wave-private)

    // ---- layer 2 + 3 fused: a = relu(H1 @ W2 + b2) . W3 + b3
    const bf16x8 ah0 = *(const bf16x8*)&H1w[jj * 64 + ((kb * 8) ^ ((jj & 7) << 3))];
    const bf16x8 ah1 = *(const bf16x8*)&H1w[jj * 64 + ((32 + kb * 8) ^ ((jj & 7) << 3))];
    float p[4] = {0.f, 0.f, 0.f, 0.f};
#pragma unroll
    for (int ct = 0; ct < 4; ct++) {
        const int wrow = (ct * 16 + jj) * 64 + kb * 8;
        bf16x8 bw0 = *(const bf16x8*)&w2t[wrow];
        bf16x8 bw1 = *(const bf16x8*)&w2t[wrow + 32];
        f32x4 acc = {0.f, 0.f, 0.f, 0.f};
        acc = __builtin_amdgcn_mfma_f32_16x16x32_bf16(ah0, bw0, acc, 0, 0, 0);
        acc = __builtin_amdgcn_mfma_f32_16x16x32_bf16(ah1, bw1, acc, 0, 0, 0);
#pragma unroll
        for (int reg = 0; reg < 4; reg++) {
            float h2 = fmaxf(acc[reg] + b2c[ct], 0.f);
            p[reg] += h2 * w3c[ct];
        }
    }
    // reduce across jj (16-lane groups; xor masks <16 stay in-group)
#pragma unroll
    for (int reg = 0; reg < 4; reg++) {
        float v = p[reg];
        v += __shfl_xor(v, 1);
        v += __shfl_xor(v, 2);
        v += __shfl_xor(v, 4);
        v += __shfl_xor(v, 8);
        if (jj == 0) a_s[w][kb * 4 + reg] = v + b3v;
    }
    // same-wave LDS RAW on a_s: compiler-handled

    // ---- scatter: num[g][col_off+j] += x[n][j] * a[n] (f32 x from L1/L2; run-length compressed)
    {
        const int i0 = w * 16;
        const int lim = min(16, nvalid - i0);
        if (lim > 0) {
            float accv = 0.f;
            int gcur = batch[base + i0];
            for (int i = 0; i < lim; i++) {
                const int n = base + i0 + i;
                const int g = batch[n];
                if (g != gcur) {
                    atomicAdd(&num[(size_t)gcur * 128 + col_off + l], accv);
                    accv = 0.f;
                    gcur = g;
                }
                accv += x[(size_t)n * 64 + l] * a_s[w][i];
            }
            atomicAdd(&num[(size_t)gcur * 128 + col_off + l], accv);
        }
    }
}

// ---------------- final MLP (f32, unchanged: negligible time) ----------------
template<int K, int LDAa, int LDBb>
__device__ __forceinline__ void tile_gemm(const float* __restrict__ As,
                                          const float* __restrict__ Bs,
                                          float acc[4][4], int n0, int j0) {
#pragma unroll 4
    for (int k0 = 0; k0 < K; k0 += 4) {
        float4 a[4], wv[4];
#pragma unroll
        for (int i = 0; i < 4; i++) a[i] = *(const float4*)&As[(n0 + i) * LDAa + k0];
#pragma unroll
        for (int kk = 0; kk < 4; kk++) wv[kk] = *(const float4*)&Bs[(k0 + kk) * LDBb + j0];
#pragma unroll
        for (int i = 0; i < 4; i++) {
            const float av0 = a[i].x, av1 = a[i].y, av2 = a[i].z, av3 = a[i].w;
            acc[i][0] += av0 * wv[0].x; acc[i][1] += av0 * wv[0].y; acc[i][2] += av0 * wv[0].z; acc[i][3] += av0 * wv[0].w;
            acc[i][0] += av1 * wv[1].x; acc[i][1] += av1 * wv[1].y; acc[i][2] += av1 * wv[1].z; acc[i][3] += av1 * wv[1].w;
            acc[i][0] += av2 * wv[2].x; acc[i][1] += av2 * wv[2].y; acc[i][2] += av2 * wv[2].z; acc[i][3] += av2 * wv[2].w;
            acc[i][0] += av3 * wv[3].x; acc[i][1] += av3 * wv[3].y; acc[i][2] += av3 * wv[3].z; acc[i][3] += av3 * wv[3].w;
        }
    }
}

__global__ __launch_bounds__(256)
void final_mlp_kernel(const float* __restrict__ num,
                      const int* __restrict__ batch1, int N1,
                      const int* __restrict__ batch2, int N2,
                      const float* __restrict__ W1, const float* __restrict__ b1,  // [128][64]
                      const float* __restrict__ W2, const float* __restrict__ b2,  // [64][64]
                      const float* __restrict__ W3, const float* __restrict__ b3,  // [64][64]
                      float* __restrict__ out) {
    __shared__ float Us[64 * LDU];
    __shared__ float W1s[128 * LDP];
    __shared__ float W2s[64 * LDP];
    __shared__ float W3s[64 * LDP];
    __shared__ float Hs[64 * LDP];
    __shared__ float inv1[64], inv2[64];

    const int t = threadIdx.x;
    const int rowbase = blockIdx.x * 64;

    if (t < 64) {
        int g = rowbase + t;
        int c = lower_bound_i(batch1, N1, g + 1) - lower_bound_i(batch1, N1, g);
        inv1[t] = 1.0f / (float)max(c, 1);
    } else if (t < 128) {
        int g = rowbase + (t - 64);
        int c = lower_bound_i(batch2, N2, g + 1) - lower_bound_i(batch2, N2, g);
        inv2[t - 64] = 1.0f / (float)max(c, 1);
    }

    {
        const float4* W1v = (const float4*)W1;
#pragma unroll
        for (int r = 0; r < 8; r++) {
            int e4 = t + 256 * r;
            int e = e4 * 4;
            int k = e / 64, j = e % 64;
            *(float4*)&W1s[k * LDP + j] = W1v[e4];
        }
        const float4* W2v = (const float4*)W2;
        const float4* W3v = (const float4*)W3;
#pragma unroll
        for (int r = 0; r < 4; r++) {
            int e4 = t + 256 * r;
            int e = e4 * 4;
            int k = e / 64, j = e % 64;
            *(float4*)&W2s[k * LDP + j] = W2v[e4];
            *(float4*)&W3s[k * LDP + j] = W3v[e4];
        }
    }
    __syncthreads();

    {
        const float4* nv = (const float4*)(num + (size_t)rowbase * 128);
#pragma unroll
        for (int r = 0; r < 8; r++) {
            int e4 = t + 256 * r;
            int e = e4 * 4;
            int row = e / 128, col = e % 128;
            float4 v = nv[e4];
            float s = (col < 64) ? inv1[row] : inv2[row];
            v.x *= s; v.y *= s; v.z *= s; v.w *= s;
            *(float4*)&Us[row * LDU + col] = v;
        }
    }
    __syncthreads();

    const int fg = t & 15, ng = t >> 4;
    const int j0 = fg * 4, n0 = ng * 4;

    float acc[4][4];
#pragma unroll
    for (int i = 0; i < 4; i++) { acc[i][0] = 0.f; acc[i][1] = 0.f; acc[i][2] = 0.f; acc[i][3] = 0.f; }
    tile_gemm<128, LDU, LDP>(Us, W1s, acc, n0, j0);
    {
        float4 bb = *(const float4*)&b1[j0];
#pragma unroll
        for (int i = 0; i < 4; i++) {
            float4 hv;
            hv.x = fmaxf(acc[i][0] + bb.x, 0.f);
            hv.y = fmaxf(acc[i][1] + bb.y, 0.f);
            hv.z = fmaxf(acc[i][2] + bb.z, 0.f);
            hv.w = fmaxf(acc[i][3] + bb.w, 0.f);
            *(float4*)&Hs[(n0 + i) * LDP + j0] = hv;
        }
    }
    __syncthreads();

#pragma unroll
    for (int i = 0; i < 4; i++) { acc[i][0] = 0.f; acc[i][1] = 0.f; acc[i][2] = 0.f; acc[i][3] = 0.f; }
    tile_gemm<64, LDP, LDP>(Hs, W2s, acc, n0, j0);
    {
        float4 bb = *(const float4*)&b2[j0];
#pragma unroll
        for (int i = 0; i < 4; i++) {
            float4 hv;
            hv.x = fmaxf(acc[i][0] + bb.x, 0.f);
            hv.y = fmaxf(acc[i][1] + bb.y, 0.f);
            hv.z = fmaxf(acc[i][2] + bb.z, 0.f);
            hv.w = fmaxf(acc[i][3] + bb.w, 0.f);
            *(float4*)&Us[(n0 + i) * LDU + j0] = hv;
        }
    }
    __syncthreads();

#pragma unroll
    for (int i = 0; i < 4; i++) { acc[i][0] = 0.f; acc[i][1] = 0.f; acc[i][2] = 0.f; acc[i][3] = 0.f; }
    tile_gemm<64, LDU, LDP>(Us, W3s, acc, n0, j0);
    {
        float4 bb = *(const float4*)&b3[j0];
#pragma unroll
        for (int i = 0; i < 4; i++) {
            float4 ov;
            ov.x = acc[i][0] + bb.x;
            ov.y = acc[i][1] + bb.y;
            ov.z = acc[i][2] + bb.z;
            ov.w = acc[i][3] + bb.w;
            *(float4*)&out[(size_t)(rowbase + n0 + i) * 64 + j0] = ov;
        }
    }
}

extern "C" void kernel_launch(void* const* d_in, const int* in_sizes, int n_in,
                              void* d_out, int out_size, void* d_ws, size_t ws_size,
                              hipStream_t stream) {
    const float* x1     = (const float*)d_in[0];
    const int*   batch1 = (const int*)d_in[1];
    const float* x2     = (const float*)d_in[2];
    const int*   batch2 = (const int*)d_in[3];
    const float* aW1    = (const float*)d_in[4];
    const float* ab1    = (const float*)d_in[5];
    const float* aW2    = (const float*)d_in[6];
    const float* ab2    = (const float*)d_in[7];
    const float* aW3    = (const float*)d_in[8];
    const float* ab3    = (const float*)d_in[9];
    const float* fW1    = (const float*)d_in[10];
    const float* fb1    = (const float*)d_in[11];
    const float* fW2    = (const float*)d_in[12];
    const float* fb2    = (const float*)d_in[13];
    const float* fW3    = (const float*)d_in[14];
    const float* fb3    = (const float*)d_in[15];

    const int N1 = in_sizes[0] / 64;
    const int N2 = in_sizes[2] / 64;

    // ws layout: [w1t bf16 8KB][w2t bf16 8KB][num f32 4096x128 = 2MB]
    unsigned short* w1t = (unsigned short*)d_ws;
    unsigned short* w2t = w1t + 64 * 64;
    float* num = (float*)((char*)d_ws + 16384);

    convert_weights_kernel<<<dim3(16), dim3(256), 0, stream>>>(aW1, aW2, w1t, w2t);
    hipMemsetAsync(num, 0, (size_t)NGRAPHS * 128 * sizeof(float), stream);

    attn_scatter_mfma<<<dim3((N1 + TILE_N - 1) / TILE_N), dim3(512), 0, stream>>>(
        x1, batch1, N1, w1t, w2t, ab1, ab2, aW3, ab3, num, 0);
    attn_scatter_mfma<<<dim3((N2 + TILE_N - 1) / TILE_N), dim3(512), 0, stream>>>(
        x2, batch2, N2, w1t, w2t, ab1, ab2, aW3, ab3, num, 64);
    final_mlp_kernel<<<dim3(NGRAPHS / 64), dim3(256), 0, stream>>>(
        num, batch1, N1, batch2, N2, fW1, fb1, fW2, fb2, fW3, fb3, (float*)d_out);
}

// Round 4
// 356.270 us; speedup vs baseline: 1.1239x; 1.1239x over previous
//
#include <hip/hip_runtime.h>

// ObjectMeanDirectAttention — Round 4: break serial latency chains.
// - All long-latency loads (x frags, scatter x rows, batch, biases, W1 frags) issued up-front.
// - Weight fragments in named registers (launch_bounds(512,4) -> VGPR cap 128) so loads are hoisted.
// - a_s LDS removed: attention scalars broadcast via __shfl from the reduce result.
// - v_cvt_pk_bf16_f32 for f32->bf16 packing.
// - LDS: per-wave swizzled 16x64 H1 only (16 KB/block).

#define NGRAPHS 4096
#define TILE_N 128
constexpr int LDP = 68;    // f32 LDS stride, final MLP
constexpr int LDU = 132;   // f32 LDS stride, 128-wide u tile

typedef short bf16x8 __attribute__((ext_vector_type(8)));
typedef float f32x4 __attribute__((ext_vector_type(4)));

__device__ __forceinline__ unsigned short f2bf(float f) {
    unsigned u = __float_as_uint(f);
    return (unsigned short)((u + 0x7FFFu + ((u >> 16) & 1u)) >> 16);  // RNE
}

__device__ __forceinline__ unsigned cvt_pk_bf16(float lo, float hi) {
    unsigned r;
    asm("v_cvt_pk_bf16_f32 %0, %1, %2" : "=v"(r) : "v"(lo), "v"(hi));
    return r;
}

union BF8 { bf16x8 v; unsigned u[4]; };

__device__ __forceinline__ int lower_bound_i(const int* __restrict__ arr, int n, int v) {
    int lo = 0, hi = n;
    while (lo < hi) {
        int mid = (lo + hi) >> 1;
        if (arr[mid] < v) lo = mid + 1; else hi = mid;
    }
    return lo;
}

// one-shot: w1t[j*64+k] = bf16(W1[k*64+j]), same for W2 (16 KB total in ws)
__global__ __launch_bounds__(256)
void convert_weights_kernel(const float* __restrict__ W1, const float* __restrict__ W2,
                            unsigned short* __restrict__ w1t, unsigned short* __restrict__ w2t) {
    int e = blockIdx.x * 256 + threadIdx.x;     // 0..4095
    int j = e >> 6, k = e & 63;
    w1t[e] = f2bf(W1[k * 64 + j]);
    w2t[e] = f2bf(W2[k * 64 + j]);
}

// ---------------- attention MLP + weighted scatter ----------------
__global__ __launch_bounds__(512, 4)
void attn_scatter_mfma(const float* __restrict__ x, const int* __restrict__ batch, int N,
                       const unsigned short* __restrict__ w1t, const unsigned short* __restrict__ w2t,
                       const float* __restrict__ b1, const float* __restrict__ b2,
                       const float* __restrict__ W3, const float* __restrict__ b3,
                       float* __restrict__ num, int col_off) {
    __shared__ unsigned short H1[8][16 * 64];   // per-wave 16x64 bf16, XOR-swizzled cols

    const int t = threadIdx.x;
    const int w = t >> 6;          // wave 0..7 owns rows 16w..16w+15
    const int l = t & 63;
    const int jj = l & 15;         // MFMA A-row / B-col index
    const int kb = l >> 4;         // k-block 0..3
    const int base = blockIdx.x * TILE_N;
    const int nvalid = min(TILE_N, N - base);
    const int row0 = base + w * 16;
    const int rowA = row0 + jj;

    // ---- issue ALL long-latency loads up-front (independent, in flight together) ----
    // (1) x A-fragments: lane (jj,kb) covers row rowA, cols kb*8..+7 and 32+kb*8..+7
    float4 v0 = make_float4(0.f, 0.f, 0.f, 0.f), v1 = v0, v2 = v0, v3 = v0;
    if (rowA < N) {
        const float* xr = x + (size_t)rowA * 64;
        v0 = *(const float4*)&xr[kb * 8];
        v1 = *(const float4*)&xr[kb * 8 + 4];
        v2 = *(const float4*)&xr[32 + kb * 8];
        v3 = *(const float4*)&xr[32 + kb * 8 + 4];
    }
    // (2) scatter operands: xp[i] = x[row0+i][l] (same cache lines as frags), batch via lane reg
    float xp[16];
#pragma unroll
    for (int i = 0; i < 16; i++) {
        xp[i] = (row0 + i < N) ? x[(size_t)(row0 + i) * 64 + l] : 0.f;
    }
    const int gidx = row0 + jj;
    const int gb = batch[gidx < N ? gidx : (N - 1)];
    // (3) biases / W3 slices
    float b1c[4], b2c[4], w3c[4];
#pragma unroll
    for (int ct = 0; ct < 4; ct++) {
        b1c[ct] = b1[ct * 16 + jj];
        b2c[ct] = b2[ct * 16 + jj];
        w3c[ct] = W3[ct * 16 + jj];
    }
    const float b3v = b3[0];
    // (4) W1 fragments (bf16, L1-resident after first block)
    bf16x8 w1f[8];
#pragma unroll
    for (int ct = 0; ct < 4; ct++) {
        const int wrow = (ct * 16 + jj) * 64 + kb * 8;
        w1f[2 * ct]     = *(const bf16x8*)&w1t[wrow];
        w1f[2 * ct + 1] = *(const bf16x8*)&w1t[wrow + 32];
    }

    // pack x fragments
    BF8 a0, a1;
    a0.u[0] = cvt_pk_bf16(v0.x, v0.y); a0.u[1] = cvt_pk_bf16(v0.z, v0.w);
    a0.u[2] = cvt_pk_bf16(v1.x, v1.y); a0.u[3] = cvt_pk_bf16(v1.z, v1.w);
    a1.u[0] = cvt_pk_bf16(v2.x, v2.y); a1.u[1] = cvt_pk_bf16(v2.z, v2.w);
    a1.u[2] = cvt_pk_bf16(v3.x, v3.y); a1.u[3] = cvt_pk_bf16(v3.z, v3.w);

    unsigned short* H1w = H1[w];

    // ---- layer 1: H1 = relu(x @ W1 + b1); C/D: col=jj, row=kb*4+reg
#pragma unroll
    for (int ct = 0; ct < 4; ct++) {
        f32x4 acc = {0.f, 0.f, 0.f, 0.f};
        acc = __builtin_amdgcn_mfma_f32_16x16x32_bf16(a0.v, w1f[2 * ct], acc, 0, 0, 0);
        acc = __builtin_amdgcn_mfma_f32_16x16x32_bf16(a1.v, w1f[2 * ct + 1], acc, 0, 0, 0);
        const int c = ct * 16 + jj;
#pragma unroll
        for (int rp = 0; rp < 2; rp++) {      // reg pairs (0,1),(2,3)
            const int r0 = kb * 4 + 2 * rp;
            float h0 = fmaxf(acc[2 * rp] + b1c[ct], 0.f);
            float h1v = fmaxf(acc[2 * rp + 1] + b1c[ct], 0.f);
            unsigned u01 = cvt_pk_bf16(h0, h1v);
            H1w[r0 * 64 + (c ^ ((r0 & 7) << 3))] = (unsigned short)(u01 & 0xffffu);
            H1w[(r0 + 1) * 64 + (c ^ (((r0 + 1) & 7) << 3))] = (unsigned short)(u01 >> 16);
        }
    }

    // W2 fragments (issue while LDS writes drain)
    bf16x8 w2f[8];
#pragma unroll
    for (int ct = 0; ct < 4; ct++) {
        const int wrow = (ct * 16 + jj) * 64 + kb * 8;
        w2f[2 * ct]     = *(const bf16x8*)&w2t[wrow];
        w2f[2 * ct + 1] = *(const bf16x8*)&w2t[wrow + 32];
    }

    // H1 is wave-private: same-wave RAW handled by compiler lgkmcnt
    const bf16x8 ah0 = *(const bf16x8*)&H1w[jj * 64 + ((kb * 8) ^ ((jj & 7) << 3))];
    const bf16x8 ah1 = *(const bf16x8*)&H1w[jj * 64 + ((32 + kb * 8) ^ ((jj & 7) << 3))];

    // ---- layer 2 + 3 fused: a = relu(H1 @ W2 + b2) . W3 + b3
    float p[4] = {0.f, 0.f, 0.f, 0.f};
#pragma unroll
    for (int ct = 0; ct < 4; ct++) {
        f32x4 acc = {0.f, 0.f, 0.f, 0.f};
        acc = __builtin_amdgcn_mfma_f32_16x16x32_bf16(ah0, w2f[2 * ct], acc, 0, 0, 0);
        acc = __builtin_amdgcn_mfma_f32_16x16x32_bf16(ah1, w2f[2 * ct + 1], acc, 0, 0, 0);
#pragma unroll
        for (int reg = 0; reg < 4; reg++) {
            float h2 = fmaxf(acc[reg] + b2c[ct], 0.f);
            p[reg] += h2 * w3c[ct];
        }
    }
    // reduce across the 16-lane jj-group; every lane ends with the group sums
#pragma unroll
    for (int reg = 0; reg < 4; reg++) {
        float v = p[reg];
        v += __shfl_xor(v, 1);
        v += __shfl_xor(v, 2);
        v += __shfl_xor(v, 4);
        v += __shfl_xor(v, 8);
        p[reg] = v + b3v;       // a for row kb*4+reg (held by all lanes of this kb group)
    }

    // ---- scatter: num[g][col_off+l] += x[row][l] * a[row], run-length compressed
    {
        const int lim = min(16, nvalid - w * 16);
        if (lim > 0) {
            float accv = 0.f;
            int gcur = __shfl(gb, 0);
#pragma unroll
            for (int i = 0; i < 16; i++) {
                if (i < lim) {
                    const int g = __shfl(gb, i);                       // batch[row0+i], wave-uniform
                    const float a_i = __shfl(p[i & 3], (i >> 2) * 16); // a[row0+i], wave-uniform lane src
                    if (g != gcur) {
                        atomicAdd(&num[(size_t)gcur * 128 + col_off + l], accv);
                        accv = 0.f;
                        gcur = g;
                    }
                    accv += xp[i] * a_i;
                }
            }
            atomicAdd(&num[(size_t)gcur * 128 + col_off + l], accv);
        }
    }
}

// ---------------- final MLP (f32, unchanged: negligible time) ----------------
template<int K, int LDAa, int LDBb>
__device__ __forceinline__ void tile_gemm(const float* __restrict__ As,
                                          const float* __restrict__ Bs,
                                          float acc[4][4], int n0, int j0) {
#pragma unroll 4
    for (int k0 = 0; k0 < K; k0 += 4) {
        float4 a[4], wv[4];
#pragma unroll
        for (int i = 0; i < 4; i++) a[i] = *(const float4*)&As[(n0 + i) * LDAa + k0];
#pragma unroll
        for (int kk = 0; kk < 4; kk++) wv[kk] = *(const float4*)&Bs[(k0 + kk) * LDBb + j0];
#pragma unroll
        for (int i = 0; i < 4; i++) {
            const float av0 = a[i].x, av1 = a[i].y, av2 = a[i].z, av3 = a[i].w;
            acc[i][0] += av0 * wv[0].x; acc[i][1] += av0 * wv[0].y; acc[i][2] += av0 * wv[0].z; acc[i][3] += av0 * wv[0].w;
            acc[i][0] += av1 * wv[1].x; acc[i][1] += av1 * wv[1].y; acc[i][2] += av1 * wv[1].z; acc[i][3] += av1 * wv[1].w;
            acc[i][0] += av2 * wv[2].x; acc[i][1] += av2 * wv[2].y; acc[i][2] += av2 * wv[2].z; acc[i][3] += av2 * wv[2].w;
            acc[i][0] += av3 * wv[3].x; acc[i][1] += av3 * wv[3].y; acc[i][2] += av3 * wv[3].z; acc[i][3] += av3 * wv[3].w;
        }
    }
}

__global__ __launch_bounds__(256)
void final_mlp_kernel(const float* __restrict__ num,
                      const int* __restrict__ batch1, int N1,
                      const int* __restrict__ batch2, int N2,
                      const float* __restrict__ W1, const float* __restrict__ b1,  // [128][64]
                      const float* __restrict__ W2, const float* __restrict__ b2,  // [64][64]
                      const float* __restrict__ W3, const float* __restrict__ b3,  // [64][64]
                      float* __restrict__ out) {
    __shared__ float Us[64 * LDU];
    __shared__ float W1s[128 * LDP];
    __shared__ float W2s[64 * LDP];
    __shared__ float W3s[64 * LDP];
    __shared__ float Hs[64 * LDP];
    __shared__ float inv1[64], inv2[64];

    const int t = threadIdx.x;
    const int rowbase = blockIdx.x * 64;

    if (t < 64) {
        int g = rowbase + t;
        int c = lower_bound_i(batch1, N1, g + 1) - lower_bound_i(batch1, N1, g);
        inv1[t] = 1.0f / (float)max(c, 1);
    } else if (t < 128) {
        int g = rowbase + (t - 64);
        int c = lower_bound_i(batch2, N2, g + 1) - lower_bound_i(batch2, N2, g);
        inv2[t - 64] = 1.0f / (float)max(c, 1);
    }

    {
        const float4* W1v = (const float4*)W1;
#pragma unroll
        for (int r = 0; r < 8; r++) {
            int e4 = t + 256 * r;
            int e = e4 * 4;
            int k = e / 64, j = e % 64;
            *(float4*)&W1s[k * LDP + j] = W1v[e4];
        }
        const float4* W2v = (const float4*)W2;
        const float4* W3v = (const float4*)W3;
#pragma unroll
        for (int r = 0; r < 4; r++) {
            int e4 = t + 256 * r;
            int e = e4 * 4;
            int k = e / 64, j = e % 64;
            *(float4*)&W2s[k * LDP + j] = W2v[e4];
            *(float4*)&W3s[k * LDP + j] = W3v[e4];
        }
    }
    __syncthreads();

    {
        const float4* nv = (const float4*)(num + (size_t)rowbase * 128);
#pragma unroll
        for (int r = 0; r < 8; r++) {
            int e4 = t + 256 * r;
            int e = e4 * 4;
            int row = e / 128, col = e % 128;
            float4 v = nv[e4];
            float s = (col < 64) ? inv1[row] : inv2[row];
            v.x *= s; v.y *= s; v.z *= s; v.w *= s;
            *(float4*)&Us[row * LDU + col] = v;
        }
    }
    __syncthreads();

    const int fg = t & 15, ng = t >> 4;
    const int j0 = fg * 4, n0 = ng * 4;

    float acc[4][4];
#pragma unroll
    for (int i = 0; i < 4; i++) { acc[i][0] = 0.f; acc[i][1] = 0.f; acc[i][2] = 0.f; acc[i][3] = 0.f; }
    tile_gemm<128, LDU, LDP>(Us, W1s, acc, n0, j0);
    {
        float4 bb = *(const float4*)&b1[j0];
#pragma unroll
        for (int i = 0; i < 4; i++) {
            float4 hv;
            hv.x = fmaxf(acc[i][0] + bb.x, 0.f);
            hv.y = fmaxf(acc[i][1] + bb.y, 0.f);
            hv.z = fmaxf(acc[i][2] + bb.z, 0.f);
            hv.w = fmaxf(acc[i][3] + bb.w, 0.f);
            *(float4*)&Hs[(n0 + i) * LDP + j0] = hv;
        }
    }
    __syncthreads();

#pragma unroll
    for (int i = 0; i < 4; i++) { acc[i][0] = 0.f; acc[i][1] = 0.f; acc[i][2] = 0.f; acc[i][3] = 0.f; }
    tile_gemm<64, LDP, LDP>(Hs, W2s, acc, n0, j0);
    {
        float4 bb = *(const float4*)&b2[j0];
#pragma unroll
        for (int i = 0; i < 4; i++) {
            float4 hv;
            hv.x = fmaxf(acc[i][0] + bb.x, 0.f);
            hv.y = fmaxf(acc[i][1] + bb.y, 0.f);
            hv.z = fmaxf(acc[i][2] + bb.z, 0.f);
            hv.w = fmaxf(acc[i][3] + bb.w, 0.f);
            *(float4*)&Us[(n0 + i) * LDU + j0] = hv;
        }
    }
    __syncthreads();

#pragma unroll
    for (int i = 0; i < 4; i++) { acc[i][0] = 0.f; acc[i][1] = 0.f; acc[i][2] = 0.f; acc[i][3] = 0.f; }
    tile_gemm<64, LDU, LDP>(Us, W3s, acc, n0, j0);
    {
        float4 bb = *(const float4*)&b3[j0];
#pragma unroll
        for (int i = 0; i < 4; i++) {
            float4 ov;
            ov.x = acc[i][0] + bb.x;
            ov.y = acc[i][1] + bb.y;
            ov.z = acc[i][2] + bb.z;
            ov.w = acc[i][3] + bb.w;
            *(float4*)&out[(size_t)(rowbase + n0 + i) * 64 + j0] = ov;
        }
    }
}

extern "C" void kernel_launch(void* const* d_in, const int* in_sizes, int n_in,
                              void* d_out, int out_size, void* d_ws, size_t ws_size,
                              hipStream_t stream) {
    const float* x1     = (const float*)d_in[0];
    const int*   batch1 = (const int*)d_in[1];
    const float* x2     = (const float*)d_in[2];
    const int*   batch2 = (const int*)d_in[3];
    const float* aW1    = (const float*)d_in[4];
    const float* ab1    = (const float*)d_in[5];
    const float* aW2    = (const float*)d_in[6];
    const float* ab2    = (const float*)d_in[7];
    const float* aW3    = (const float*)d_in[8];
    const float* ab3    = (const float*)d_in[9];
    const float* fW1    = (const float*)d_in[10];
    const float* fb1    = (const float*)d_in[11];
    const float* fW2    = (const float*)d_in[12];
    const float* fb2    = (const float*)d_in[13];
    const float* fW3    = (const float*)d_in[14];
    const float* fb3    = (const float*)d_in[15];

    const int N1 = in_sizes[0] / 64;
    const int N2 = in_sizes[2] / 64;

    // ws layout: [w1t bf16 8KB][w2t bf16 8KB][num f32 4096x128 = 2MB]
    unsigned short* w1t = (unsigned short*)d_ws;
    unsigned short* w2t = w1t + 64 * 64;
    float* num = (float*)((char*)d_ws + 16384);

    convert_weights_kernel<<<dim3(16), dim3(256), 0, stream>>>(aW1, aW2, w1t, w2t);
    hipMemsetAsync(num, 0, (size_t)NGRAPHS * 128 * sizeof(float), stream);

    attn_scatter_mfma<<<dim3((N1 + TILE_N - 1) / TILE_N), dim3(512), 0, stream>>>(
        x1, batch1, N1, w1t, w2t, ab1, ab2, aW3, ab3, num, 0);
    attn_scatter_mfma<<<dim3((N2 + TILE_N - 1) / TILE_N), dim3(512), 0, stream>>>(
        x2, batch2, N2, w1t, w2t, ab1, ab2, aW3, ab3, num, 64);
    final_mlp_kernel<<<dim3(NGRAPHS / 64), dim3(256), 0, stream>>>(
        num, batch1, N1, batch2, N2, fW1, fb1, fW2, fb2, fW3, fb3, (float*)d_out);
}

// Round 5
// 327.985 us; speedup vs baseline: 1.2209x; 1.0862x over previous
//
#include <hip/hip_runtime.h>

// ObjectMeanDirectAttention — Round 5: 64 nodes/wave + operand-swapped MFMA, zero LDS.
// - Swapped L1: D = mfma(W1p-as-A, X-as-B) = H1^T -> each lane holds 16 feats of ITS node.
//   Weight rows permuted (pi) so packed H1 pairs form the L2 B-fragment directly: no LDS,
//   no cross-lane exchange, no barriers in the attn kernel at all.
// - 4 independent 16-node groups per wave (512 nodes/block): weights/coefs amortized 4x,
//   4 MFMA chains of ILP. Both inputs merged into one launch (block-id split).
// - Biases folded into MFMA C-init. Layer-3 reduce = 2 shfl_xor (16,32).

#define NGRAPHS 4096
constexpr int LDP = 68;    // f32 LDS stride, final MLP
constexpr int LDU = 132;   // f32 LDS stride, 128-wide u tile

typedef short bf16x8 __attribute__((ext_vector_type(8)));
typedef float f32x4 __attribute__((ext_vector_type(4)));

union BF8 { bf16x8 v; unsigned u[4]; };

__device__ __forceinline__ unsigned short f2bf(float f) {
    unsigned u = __float_as_uint(f);
    return (unsigned short)((u + 0x7FFFu + ((u >> 16) & 1u)) >> 16);  // RNE
}

__device__ __forceinline__ unsigned cvt_pk_bf16(float lo, float hi) {
    unsigned r;
    asm("v_cvt_pk_bf16_f32 %0, %1, %2" : "=v"(r) : "v"(lo), "v"(hi));
    return r;
}

__device__ __forceinline__ int lower_bound_i(const int* __restrict__ arr, int n, int v) {
    int lo = 0, hi = n;
    while (lo < hi) {
        int mid = (lo + hi) >> 1;
        if (arr[mid] < v) lo = mid + 1; else hi = mid;
    }
    return lo;
}

// one-shot weight prep:
//   w1p[r*64+k] = bf16(W1[k][pi(r)]) with pi(16ct+4kb+reg) = 32*(ct>>1)+8kb+4*(ct&1)+reg
//   w2t[r*64+k] = bf16(W2[k][r])
__global__ __launch_bounds__(256)
void convert_weights_kernel(const float* __restrict__ W1, const float* __restrict__ W2,
                            unsigned short* __restrict__ w1p, unsigned short* __restrict__ w2t) {
    int e = blockIdx.x * 256 + threadIdx.x;     // 0..4095
    int r = e >> 6, k = e & 63;
    int ct = r >> 4, kb = (r >> 2) & 3, reg = r & 3;
    int pi = 32 * (ct >> 1) + 8 * kb + 4 * (ct & 1) + reg;
    w1p[e] = f2bf(W1[k * 64 + pi]);
    w2t[e] = f2bf(W2[k * 64 + r]);
}

// ---------------- attention MLP + weighted scatter (both inputs, one launch) ----------------
__global__ __launch_bounds__(512, 4)
void attn_scatter_mfma(const float* __restrict__ x1, const int* __restrict__ batch1, int N1, int nblk1,
                       const float* __restrict__ x2, const int* __restrict__ batch2, int N2,
                       const unsigned short* __restrict__ w1p, const unsigned short* __restrict__ w2t,
                       const float* __restrict__ b1, const float* __restrict__ b2,
                       const float* __restrict__ W3, const float* __restrict__ b3,
                       float* __restrict__ num) {
    const float* x; const int* batch; int N, col_off, blk;
    if ((int)blockIdx.x < nblk1) { x = x1; batch = batch1; N = N1; col_off = 0;  blk = blockIdx.x; }
    else                         { x = x2; batch = batch2; N = N2; col_off = 64; blk = blockIdx.x - nblk1; }

    const int t = threadIdx.x;
    const int w = t >> 6, l = t & 63;
    const int jj = l & 15, kb = l >> 4;
    const int base = blk * 512 + w * 64;          // this wave's 64 nodes

    // ---- per-wave coefficient loads (lane-dependent on kb; L1-hot after first waves) ----
    // L1 bias at permuted feats pi(ct,kb,reg): ct0->8kb+reg, ct1->8kb+4+reg, ct2->32+8kb+reg, ct3->36+8kb+reg
    f32x4 b1q[4];
    b1q[0] = *(const f32x4*)&b1[8 * kb];
    b1q[1] = *(const f32x4*)&b1[8 * kb + 4];
    b1q[2] = *(const f32x4*)&b1[32 + 8 * kb];
    b1q[3] = *(const f32x4*)&b1[32 + 8 * kb + 4];
    // L2 coefs at feats 16ct+4kb+reg
    f32x4 b2q[4];
    float4 w3q[4];
#pragma unroll
    for (int ct = 0; ct < 4; ct++) {
        b2q[ct] = *(const f32x4*)&b2[ct * 16 + 4 * kb];
        w3q[ct] = *(const float4*)&W3[ct * 16 + 4 * kb];
    }
    const float b3v = b3[0];

    // ---- per-wave weight fragments (bf16, L1-resident) ----
    // A-operand rows: tile ct, lane jj -> row 16ct+jj, k = kb*8..+7 (+32 for second half)
    bf16x8 w1f[8], w2f[8];
#pragma unroll
    for (int ct = 0; ct < 4; ct++) {
        const int wrow = (ct * 16 + jj) * 64 + kb * 8;
        w1f[2 * ct]     = *(const bf16x8*)&w1p[wrow];
        w1f[2 * ct + 1] = *(const bf16x8*)&w1p[wrow + 32];
        w2f[2 * ct]     = *(const bf16x8*)&w2t[wrow];
        w2f[2 * ct + 1] = *(const bf16x8*)&w2t[wrow + 32];
    }

    // ---- 4 independent 16-node groups ----
    float aq[4];
    int   gb[4];
#pragma unroll
    for (int q = 0; q < 4; ++q) {
        const int row = base + q * 16 + jj;
        // B-operand (X^T): lane (jj,kb) holds X[node jj][k=kb*8..+7] and [32+kb*8..+7]
        float4 v0 = make_float4(0.f, 0.f, 0.f, 0.f), v1 = v0, v2 = v0, v3 = v0;
        if (row < N) {
            const float* xr = x + (size_t)row * 64;
            v0 = *(const float4*)&xr[kb * 8];
            v1 = *(const float4*)&xr[kb * 8 + 4];
            v2 = *(const float4*)&xr[32 + kb * 8];
            v3 = *(const float4*)&xr[32 + kb * 8 + 4];
        }
        gb[q] = batch[row < N ? row : (N - 1)];

        BF8 xb0, xb1;
        xb0.u[0] = cvt_pk_bf16(v0.x, v0.y); xb0.u[1] = cvt_pk_bf16(v0.z, v0.w);
        xb0.u[2] = cvt_pk_bf16(v1.x, v1.y); xb0.u[3] = cvt_pk_bf16(v1.z, v1.w);
        xb1.u[0] = cvt_pk_bf16(v2.x, v2.y); xb1.u[1] = cvt_pk_bf16(v2.z, v2.w);
        xb1.u[2] = cvt_pk_bf16(v3.x, v3.y); xb1.u[3] = cvt_pk_bf16(v3.z, v3.w);

        // layer 1 (swapped): D = W1p @ X^T + b1 -> lane holds H1pre[node jj][pi(ct,kb,reg)]
        unsigned ph[8];
#pragma unroll
        for (int ct = 0; ct < 4; ++ct) {
            f32x4 acc = b1q[ct];
            acc = __builtin_amdgcn_mfma_f32_16x16x32_bf16(w1f[2 * ct],     xb0.v, acc, 0, 0, 0);
            acc = __builtin_amdgcn_mfma_f32_16x16x32_bf16(w1f[2 * ct + 1], xb1.v, acc, 0, 0, 0);
            ph[2 * ct]     = cvt_pk_bf16(fmaxf(acc[0], 0.f), fmaxf(acc[1], 0.f));
            ph[2 * ct + 1] = cvt_pk_bf16(fmaxf(acc[2], 0.f), fmaxf(acc[3], 0.f));
        }
        // pi ordering makes ph exactly the L2 B-fragment: bh0 = feats 8kb..+7, bh1 = 32+8kb..+7
        BF8 bh0, bh1;
        bh0.u[0] = ph[0]; bh0.u[1] = ph[1]; bh0.u[2] = ph[2]; bh0.u[3] = ph[3];
        bh1.u[0] = ph[4]; bh1.u[1] = ph[5]; bh1.u[2] = ph[6]; bh1.u[3] = ph[7];

        // layer 2+3 (swapped): lane holds H2pre[node jj][16ct+4kb+reg]
        float p = 0.f;
#pragma unroll
        for (int ct = 0; ct < 4; ++ct) {
            f32x4 acc = b2q[ct];
            acc = __builtin_amdgcn_mfma_f32_16x16x32_bf16(w2f[2 * ct],     bh0.v, acc, 0, 0, 0);
            acc = __builtin_amdgcn_mfma_f32_16x16x32_bf16(w2f[2 * ct + 1], bh1.v, acc, 0, 0, 0);
            p += fmaxf(acc[0], 0.f) * w3q[ct].x + fmaxf(acc[1], 0.f) * w3q[ct].y
               + fmaxf(acc[2], 0.f) * w3q[ct].z + fmaxf(acc[3], 0.f) * w3q[ct].w;
        }
        // reduce the 4 kb-lane partials of node jj
        p += __shfl_xor(p, 16);
        p += __shfl_xor(p, 32);
        aq[q] = p + b3v;          // a[node jj], held by all 4 kb copies
    }

    // ---- scatter: num[g][col_off+l] += x[n][l] * a[n], run-length over 64 nodes ----
    const int nv = min(64, N - base);
    if (nv > 0) {
        float accv = 0.f;
        int gcur = __shfl(gb[0], 0);
#pragma unroll
        for (int q = 0; q < 4; ++q) {
            float xq[16];
#pragma unroll
            for (int i = 0; i < 16; ++i) {
                const int n = base + q * 16 + i;
                xq[i] = (n < N) ? x[(size_t)n * 64 + l] : 0.f;
            }
#pragma unroll
            for (int i = 0; i < 16; ++i) {
                const int n = base + q * 16 + i;
                if (n < N) {                                    // wave-uniform
                    const int g = __shfl(gb[q], i);             // batch[n]
                    const float ai = __shfl(aq[q], i);          // a[n]
                    if (g != gcur) {                            // wave-uniform, rare
                        atomicAdd(&num[(size_t)gcur * 128 + col_off + l], accv);
                        accv = 0.f;
                        gcur = g;
                    }
                    accv += xq[i] * ai;
                }
            }
        }
        atomicAdd(&num[(size_t)gcur * 128 + col_off + l], accv);
    }
}

// ---------------- final MLP (f32, unchanged: negligible time) ----------------
template<int K, int LDAa, int LDBb>
__device__ __forceinline__ void tile_gemm(const float* __restrict__ As,
                                          const float* __restrict__ Bs,
                                          float acc[4][4], int n0, int j0) {
#pragma unroll 4
    for (int k0 = 0; k0 < K; k0 += 4) {
        float4 a[4], wv[4];
#pragma unroll
        for (int i = 0; i < 4; i++) a[i] = *(const float4*)&As[(n0 + i) * LDAa + k0];
#pragma unroll
        for (int kk = 0; kk < 4; kk++) wv[kk] = *(const float4*)&Bs[(k0 + kk) * LDBb + j0];
#pragma unroll
        for (int i = 0; i < 4; i++) {
            const float av0 = a[i].x, av1 = a[i].y, av2 = a[i].z, av3 = a[i].w;
            acc[i][0] += av0 * wv[0].x; acc[i][1] += av0 * wv[0].y; acc[i][2] += av0 * wv[0].z; acc[i][3] += av0 * wv[0].w;
            acc[i][0] += av1 * wv[1].x; acc[i][1] += av1 * wv[1].y; acc[i][2] += av1 * wv[1].z; acc[i][3] += av1 * wv[1].w;
            acc[i][0] += av2 * wv[2].x; acc[i][1] += av2 * wv[2].y; acc[i][2] += av2 * wv[2].z; acc[i][3] += av2 * wv[2].w;
            acc[i][0] += av3 * wv[3].x; acc[i][1] += av3 * wv[3].y; acc[i][2] += av3 * wv[3].z; acc[i][3] += av3 * wv[3].w;
        }
    }
}

__global__ __launch_bounds__(256)
void final_mlp_kernel(const float* __restrict__ num,
                      const int* __restrict__ batch1, int N1,
                      const int* __restrict__ batch2, int N2,
                      const float* __restrict__ W1, const float* __restrict__ b1,  // [128][64]
                      const float* __restrict__ W2, const float* __restrict__ b2,  // [64][64]
                      const float* __restrict__ W3, const float* __restrict__ b3,  // [64][64]
                      float* __restrict__ out) {
    __shared__ float Us[64 * LDU];
    __shared__ float W1s[128 * LDP];
    __shared__ float W2s[64 * LDP];
    __shared__ float W3s[64 * LDP];
    __shared__ float Hs[64 * LDP];
    __shared__ float inv1[64], inv2[64];

    const int t = threadIdx.x;
    const int rowbase = blockIdx.x * 64;

    if (t < 64) {
        int g = rowbase + t;
        int c = lower_bound_i(batch1, N1, g + 1) - lower_bound_i(batch1, N1, g);
        inv1[t] = 1.0f / (float)max(c, 1);
    } else if (t < 128) {
        int g = rowbase + (t - 64);
        int c = lower_bound_i(batch2, N2, g + 1) - lower_bound_i(batch2, N2, g);
        inv2[t - 64] = 1.0f / (float)max(c, 1);
    }

    {
        const float4* W1v = (const float4*)W1;
#pragma unroll
        for (int r = 0; r < 8; r++) {
            int e4 = t + 256 * r;
            int e = e4 * 4;
            int k = e / 64, j = e % 64;
            *(float4*)&W1s[k * LDP + j] = W1v[e4];
        }
        const float4* W2v = (const float4*)W2;
        const float4* W3v = (const float4*)W3;
#pragma unroll
        for (int r = 0; r < 4; r++) {
            int e4 = t + 256 * r;
            int e = e4 * 4;
            int k = e / 64, j = e % 64;
            *(float4*)&W2s[k * LDP + j] = W2v[e4];
            *(float4*)&W3s[k * LDP + j] = W3v[e4];
        }
    }
    __syncthreads();

    {
        const float4* nv = (const float4*)(num + (size_t)rowbase * 128);
#pragma unroll
        for (int r = 0; r < 8; r++) {
            int e4 = t + 256 * r;
            int e = e4 * 4;
            int row = e / 128, col = e % 128;
            float4 v = nv[e4];
            float s = (col < 64) ? inv1[row] : inv2[row];
            v.x *= s; v.y *= s; v.z *= s; v.w *= s;
            *(float4*)&Us[row * LDU + col] = v;
        }
    }
    __syncthreads();

    const int fg = t & 15, ng = t >> 4;
    const int j0 = fg * 4, n0 = ng * 4;

    float acc[4][4];
#pragma unroll
    for (int i = 0; i < 4; i++) { acc[i][0] = 0.f; acc[i][1] = 0.f; acc[i][2] = 0.f; acc[i][3] = 0.f; }
    tile_gemm<128, LDU, LDP>(Us, W1s, acc, n0, j0);
    {
        float4 bb = *(const float4*)&b1[j0];
#pragma unroll
        for (int i = 0; i < 4; i++) {
            float4 hv;
            hv.x = fmaxf(acc[i][0] + bb.x, 0.f);
            hv.y = fmaxf(acc[i][1] + bb.y, 0.f);
            hv.z = fmaxf(acc[i][2] + bb.z, 0.f);
            hv.w = fmaxf(acc[i][3] + bb.w, 0.f);
            *(float4*)&Hs[(n0 + i) * LDP + j0] = hv;
        }
    }
    __syncthreads();

#pragma unroll
    for (int i = 0; i < 4; i++) { acc[i][0] = 0.f; acc[i][1] = 0.f; acc[i][2] = 0.f; acc[i][3] = 0.f; }
    tile_gemm<64, LDP, LDP>(Hs, W2s, acc, n0, j0);
    {
        float4 bb = *(const float4*)&b2[j0];
#pragma unroll
        for (int i = 0; i < 4; i++) {
            float4 hv;
            hv.x = fmaxf(acc[i][0] + bb.x, 0.f);
            hv.y = fmaxf(acc[i][1] + bb.y, 0.f);
            hv.z = fmaxf(acc[i][2] + bb.z, 0.f);
            hv.w = fmaxf(acc[i][3] + bb.w, 0.f);
            *(float4*)&Us[(n0 + i) * LDU + j0] = hv;
        }
    }
    __syncthreads();

#pragma unroll
    for (int i = 0; i < 4; i++) { acc[i][0] = 0.f; acc[i][1] = 0.f; acc[i][2] = 0.f; acc[i][3] = 0.f; }
    tile_gemm<64, LDU, LDP>(Us, W3s, acc, n0, j0);
    {
        float4 bb = *(const float4*)&b3[j0];
#pragma unroll
        for (int i = 0; i < 4; i++) {
            float4 ov;
            ov.x = acc[i][0] + bb.x;
            ov.y = acc[i][1] + bb.y;
            ov.z = acc[i][2] + bb.z;
            ov.w = acc[i][3] + bb.w;
            *(float4*)&out[(size_t)(rowbase + n0 + i) * 64 + j0] = ov;
        }
    }
}

extern "C" void kernel_launch(void* const* d_in, const int* in_sizes, int n_in,
                              void* d_out, int out_size, void* d_ws, size_t ws_size,
                              hipStream_t stream) {
    const float* x1     = (const float*)d_in[0];
    const int*   batch1 = (const int*)d_in[1];
    const float* x2     = (const float*)d_in[2];
    const int*   batch2 = (const int*)d_in[3];
    const float* aW1    = (const float*)d_in[4];
    const float* ab1    = (const float*)d_in[5];
    const float* aW2    = (const float*)d_in[6];
    const float* ab2    = (const float*)d_in[7];
    const float* aW3    = (const float*)d_in[8];
    const float* ab3    = (const float*)d_in[9];
    const float* fW1    = (const float*)d_in[10];
    const float* fb1    = (const float*)d_in[11];
    const float* fW2    = (const float*)d_in[12];
    const float* fb2    = (const float*)d_in[13];
    const float* fW3    = (const float*)d_in[14];
    const float* fb3    = (const float*)d_in[15];

    const int N1 = in_sizes[0] / 64;
    const int N2 = in_sizes[2] / 64;

    // ws layout: [w1p bf16 8KB][w2t bf16 8KB][num f32 4096x128 = 2MB]
    unsigned short* w1p = (unsigned short*)d_ws;
    unsigned short* w2t = w1p + 64 * 64;
    float* num = (float*)((char*)d_ws + 16384);

    convert_weights_kernel<<<dim3(16), dim3(256), 0, stream>>>(aW1, aW2, w1p, w2t);
    hipMemsetAsync(num, 0, (size_t)NGRAPHS * 128 * sizeof(float), stream);

    const int nblk1 = (N1 + 511) / 512;
    const int nblk2 = (N2 + 511) / 512;
    attn_scatter_mfma<<<dim3(nblk1 + nblk2), dim3(512), 0, stream>>>(
        x1, batch1, N1, nblk1, x2, batch2, N2,
        w1p, w2t, ab1, ab2, aW3, ab3, num);
    final_mlp_kernel<<<dim3(NGRAPHS / 64), dim3(256), 0, stream>>>(
        num, batch1, N1, batch2, N2, fW1, fb1, fW2, fb2, fW3, fb3, (float*)d_out);
}